// Round 6
// baseline (244.330 us; speedup 1.0000x reference)
//
#include <hip/hip_runtime.h>

#define B_ 8192
#define IN_ 1024
#define OUT_ 256
#define E_ 16
#define KTOP 3
#define H_ 512
#define MAXSLOTS 26624   // 24576 + 16*127 rounded up
#define NTILES 208       // MAXSLOTS / 128
#define HBLK 16          // dispatch blocks

typedef __bf16 bf16;
typedef __bf16 bf16x4 __attribute__((ext_vector_type(4)));
typedef __bf16 bf16x8 __attribute__((ext_vector_type(8)));
typedef float f32x4 __attribute__((ext_vector_type(4)));

// async global->LDS, 16B per lane. LDS dest must be wave-uniform base + lane*16.
__device__ __forceinline__ void async16(const bf16* g, bf16* l) {
    __builtin_amdgcn_global_load_lds(
        (const __attribute__((address_space(1))) void*)g,
        (__attribute__((address_space(3))) void*)l,
        16, 0, 0);
}

// ---------------- setup: W1/W2 transpose+convert, row_ids/-1, wgT, zero_row, tile_expert ----------------
// blocks [0,2048): W1 tiles; [2048,2560): W2 tiles; [2560,2664): row_ids;
// [2664,2728): wgT; 2728: zero_row + tile_expert.
__global__ __launch_bounds__(256) void k_setup(
    const float* __restrict__ W1, bf16* __restrict__ w1t,
    const float* __restrict__ W2, bf16* __restrict__ w2t,
    int* __restrict__ row_ids, const float* __restrict__ wg, float* __restrict__ wgT,
    bf16* __restrict__ zero_row, int* __restrict__ tile_expert) {
    int bx = blockIdx.x;
    int t = threadIdx.x;
    if (bx >= 2560) {
        if (bx < 2664) {            // row_ids = -1
            int id = (bx - 2560) * 256 + t;
            if (id < MAXSLOTS) row_ids[id] = -1;
        } else if (bx < 2728) {     // wgT[e][j] = wg[j][e]
            int id = (bx - 2664) * 256 + t;
            int e = id >> 10, j = id & 1023;
            wgT[id] = wg[j * E_ + e];
        } else {                    // zero_row + tile_expert
#pragma unroll
            for (int i = 0; i < 4; i++) zero_row[t * 4 + i] = (bf16)0.f;
            if (t < NTILES) tile_expert[t] = -1;
        }
        return;
    }
    __shared__ float tile[64][65];
    const float* in; bf16* out; int Kd, Nd, e, tk, tn;
    if (bx < 2048) {            // W1: 16 experts x (16 x 8) tiles
        in = W1; out = w1t; Kd = IN_; Nd = H_;
        e = bx >> 7; int tt = bx & 127; tk = tt >> 3; tn = tt & 7;
    } else {                    // W2: 16 experts x (8 x 4) tiles
        int b2x = bx - 2048;
        in = W2; out = w2t; Kd = H_; Nd = OUT_;
        e = b2x >> 5; int tt = b2x & 31; tk = tt >> 2; tn = tt & 3;
    }
    int r = t >> 6, c = t & 63;
    const float* src = in + ((size_t)e * Kd + tk * 64) * Nd + (size_t)tn * 64;
#pragma unroll
    for (int i = 0; i < 16; i++) {
        int rr = r + i * 4;
        tile[rr][c] = src[(size_t)rr * Nd + c];
    }
    __syncthreads();
    bf16* dst = out + ((size_t)e * Nd + tn * 64) * Kd + (size_t)tk * 64;
#pragma unroll
    for (int i = 0; i < 16; i++) {
        int rr = r + i * 4;
        dst[(size_t)rr * Kd + c] = (bf16)tile[c][rr];
    }
}

// ---------------- gating: coalesced wgT reads, top-3 softmax, emit x as bf16 ----------------
__global__ __launch_bounds__(256) void k_gating(
    const float* __restrict__ x, const float* __restrict__ wgT,
    bf16* __restrict__ xbf, int* __restrict__ top_idx, float* __restrict__ top_gate) {
    int t = threadIdx.x;
    int row = blockIdx.x * 4 + (t >> 6);
    int lane = t & 63;
    float acc[16];
#pragma unroll
    for (int e = 0; e < 16; e++) acc[e] = 0.f;
    const float4* x4p = (const float4*)(x + (size_t)row * IN_);
    const float4* w4 = (const float4*)wgT;
#pragma unroll
    for (int it = 0; it < 4; it++) {
        int j0 = it * 64 + lane;
        float4 xv = x4p[j0];
        bf16x4 xb;
        xb[0] = (bf16)xv.x; xb[1] = (bf16)xv.y; xb[2] = (bf16)xv.z; xb[3] = (bf16)xv.w;
        *(bf16x4*)(xbf + (size_t)row * IN_ + j0 * 4) = xb;
#pragma unroll
        for (int e = 0; e < 16; e++) {
            float4 wv = w4[e * 256 + j0];
            acc[e] += xv.x * wv.x + xv.y * wv.y + xv.z * wv.z + xv.w * wv.w;
        }
    }
#pragma unroll
    for (int e = 0; e < 16; e++) {
#pragma unroll
        for (int s = 32; s > 0; s >>= 1) acc[e] += __shfl_xor(acc[e], s, 64);
    }
    if (lane == 0) {
        float v[16];
#pragma unroll
        for (int e = 0; e < 16; e++) v[e] = acc[e];
        int idx[KTOP];
        float val[KTOP];
#pragma unroll
        for (int k = 0; k < KTOP; k++) {
            int best = 0;
            float bv = v[0];
            for (int e = 1; e < 16; e++) {
                if (v[e] > bv) { bv = v[e]; best = e; }
            }
            idx[k] = best; val[k] = bv; v[best] = -1e30f;
        }
        float e1 = __expf(val[1] - val[0]);
        float e2 = __expf(val[2] - val[0]);
        float inv = 1.f / (1.f + e1 + e2);
        float g[KTOP] = {inv, e1 * inv, e2 * inv};
#pragma unroll
        for (int k = 0; k < KTOP; k++) {
            top_idx[row * KTOP + k] = idx[k];
            top_gate[row * KTOP + k] = g[k];
        }
    }
}

// ---------------- dispatch: hist + scan + scatter fused (16 blocks, zero global atomics) ----------------
// Each block redundantly histograms all 24576 assignments (98 KB, L2-hot),
// derives global offsets + its own prefix base, then scatters its 1536-chunk.
__global__ __launch_bounds__(256) void k_dispatch(
    const int* __restrict__ top_idx, const float* __restrict__ top_gate,
    int* __restrict__ counts, int* __restrict__ tile_expert,
    int* __restrict__ row_ids, int* __restrict__ rowslot,
    float* __restrict__ partial_imp) {
    __shared__ int wtot[4][16];
    __shared__ int wpre[4][16];
    __shared__ int sbase[16];
    __shared__ int lcnt[16];
    __shared__ float limp[16];
    int t = threadIdx.x;
    int w = t >> 6;
    int blk = blockIdx.x;
    int tot[16], pre[16];
#pragma unroll
    for (int k = 0; k < 16; k++) { tot[k] = 0; pre[k] = 0; }
    for (int c = 0; c < HBLK; c++) {
#pragma unroll
        for (int j = 0; j < 6; j++) {
            int e = top_idx[c * 1536 + j * 256 + t];
#pragma unroll
            for (int k = 0; k < 16; k++) {
                int n = (int)__popcll(__ballot(e == k));
                tot[k] += n;
                if (c < blk) pre[k] += n;
            }
        }
    }
    int lane = t & 63;
    if (lane == 0) {
#pragma unroll
        for (int k = 0; k < 16; k++) { wtot[w][k] = tot[k]; wpre[w][k] = pre[k]; }
    }
    if (t < 16) { lcnt[t] = 0; limp[t] = 0.f; }
    __syncthreads();
    if (t < 16) {
        // serial-ish per-expert offset: off[e] = sum_{e'<e} pad(count[e'])
        int off = 0;
        for (int e = 0; e < 16; e++) {
            int ce = wtot[0][e] + wtot[1][e] + wtot[2][e] + wtot[3][e];
            if (e == t) break;
            off += (ce + 127) & ~127;
        }
        int cnt_t = wtot[0][t] + wtot[1][t] + wtot[2][t] + wtot[3][t];
        int pre_t = wpre[0][t] + wpre[1][t] + wpre[2][t] + wpre[3][t];
        sbase[t] = off + pre_t;
        if (blk == 0) {
            counts[t] = cnt_t;
            int pd = (cnt_t + 127) & ~127;
            for (int tt = off >> 7; tt < (off + pd) >> 7; ++tt) tile_expert[tt] = t;
        }
    }
    __syncthreads();
#pragma unroll
    for (int j = 0; j < 6; j++) {
        int gid = blk * 1536 + j * 256 + t;
        int e = top_idx[gid];
        float g = top_gate[gid];
        int rank = atomicAdd(&lcnt[e], 1);
        atomicAdd(&limp[e], g);
        int slot = sbase[e] + rank;
        row_ids[slot] = gid / KTOP;
        rowslot[gid] = slot;
    }
    __syncthreads();
    if (t < 16) partial_imp[blk * 16 + t] = limp[t];
}

// ======================= GEMMs: BK=64, XOR swizzle, grid x=tile (XCD-sibling L2 reuse) =======================
// Sibling N-tile blocks of one slot-tile have linear ids differing by NTILES=208 == 0 mod 8
// -> same XCD -> gathered A rows fetched into that XCD's L2 once, reused by siblings.

// ---------------- GEMM1: h = relu(gather(x) @ W1[e] + b1[e]) -> bf16 ----------------
__global__ __launch_bounds__(256) void k_gemm1(
    const bf16* __restrict__ xbf, const bf16* __restrict__ w1t,
    const float* __restrict__ b1, const int* __restrict__ row_ids,
    const int* __restrict__ tile_expert, const bf16* __restrict__ zero_row,
    bf16* __restrict__ h) {
    int e = tile_expert[blockIdx.x];
    if (e < 0) return;
    int slot_base = blockIdx.x * 128;
    int nbase = blockIdx.y * 128;
    __shared__ __align__(16) bf16 As[128 * 64];  // 16 KB
    __shared__ __align__(16) bf16 Bs[128 * 64];  // 16 KB
    int t = threadIdx.x;
    int rmod = (t >> 3) & 7;
    int cglob = (t & 7) ^ rmod;
    const bf16* gA[4];
    const bf16* gB[4];
#pragma unroll
    for (int j = 0; j < 4; j++) {
        int m = j * 32 + (t >> 3);
        int rid = row_ids[slot_base + m];
        gA[j] = ((rid >= 0) ? xbf + (size_t)rid * IN_ : zero_row) + cglob * 8;
        gB[j] = w1t + ((size_t)e * H_ + nbase + m) * IN_ + cglob * 8;
    }
    int w = t >> 6, lane = t & 63;
    int wm = (w >> 1) * 64, wn = (w & 1) * 64;
    int lm = lane & 15, lq = lane >> 4;
    f32x4 acc[4][4] = {};
    for (int k0 = 0; k0 < IN_; k0 += 64) {
#pragma unroll
        for (int j = 0; j < 4; j++) {
            async16(gA[j] + k0, As + (j * 256 + t) * 8);
            async16(gB[j] + k0, Bs + (j * 256 + t) * 8);
        }
        __syncthreads();
        const bf16x8* Av = (const bf16x8*)As;
        const bf16x8* Bv = (const bf16x8*)Bs;
#pragma unroll
        for (int ks = 0; ks < 2; ks++) {
            int kc = ks * 4 + lq;
            bf16x8 af[4], bfv[4];
#pragma unroll
            for (int i = 0; i < 4; i++) {
                int row = wm + i * 16 + lm;
                af[i] = Av[row * 8 + (kc ^ (row & 7))];
            }
#pragma unroll
            for (int i = 0; i < 4; i++) {
                int row = wn + i * 16 + lm;
                bfv[i] = Bv[row * 8 + (kc ^ (row & 7))];
            }
#pragma unroll
            for (int mi = 0; mi < 4; mi++)
#pragma unroll
                for (int ni = 0; ni < 4; ni++)
                    acc[mi][ni] = __builtin_amdgcn_mfma_f32_16x16x32_bf16(af[mi], bfv[ni], acc[mi][ni], 0, 0, 0);
        }
        __syncthreads();
    }
#pragma unroll
    for (int mi = 0; mi < 4; mi++) {
#pragma unroll
        for (int ni = 0; ni < 4; ni++) {
            int colg = nbase + wn + ni * 16 + lm;
            float bias = b1[e * H_ + colg];
#pragma unroll
            for (int r = 0; r < 4; r++) {
                int rowl = wm + mi * 16 + lq * 4 + r;
                float v = acc[mi][ni][r] + bias;
                v = v > 0.f ? v : 0.f;
                h[(size_t)(slot_base + rowl) * H_ + colg] = (bf16)v;
            }
        }
    }
}

// ---------------- GEMM2: eout[slot] = h[slot] @ W2[e] + b2[e]  (f32) ----------------
__global__ __launch_bounds__(256) void k_gemm2(
    const bf16* __restrict__ h, const bf16* __restrict__ w2t,
    const float* __restrict__ b2, const int* __restrict__ tile_expert,
    float* __restrict__ eout) {
    int e = tile_expert[blockIdx.x];
    if (e < 0) return;
    int slot_base = blockIdx.x * 128;
    int nbase = blockIdx.y * 128;
    __shared__ __align__(16) bf16 As[128 * 64];
    __shared__ __align__(16) bf16 Bs[128 * 64];
    int t = threadIdx.x;
    int rmod = (t >> 3) & 7;
    int cglob = (t & 7) ^ rmod;
    const bf16* gA[4];
    const bf16* gB[4];
#pragma unroll
    for (int j = 0; j < 4; j++) {
        int m = j * 32 + (t >> 3);
        gA[j] = h + (size_t)(slot_base + m) * H_ + cglob * 8;
        gB[j] = w2t + ((size_t)e * OUT_ + nbase + m) * H_ + cglob * 8;
    }
    int w = t >> 6, lane = t & 63;
    int wm = (w >> 1) * 64, wn = (w & 1) * 64;
    int lm = lane & 15, lq = lane >> 4;
    f32x4 acc[4][4] = {};
    for (int k0 = 0; k0 < H_; k0 += 64) {
#pragma unroll
        for (int j = 0; j < 4; j++) {
            async16(gA[j] + k0, As + (j * 256 + t) * 8);
            async16(gB[j] + k0, Bs + (j * 256 + t) * 8);
        }
        __syncthreads();
        const bf16x8* Av = (const bf16x8*)As;
        const bf16x8* Bv = (const bf16x8*)Bs;
#pragma unroll
        for (int ks = 0; ks < 2; ks++) {
            int kc = ks * 4 + lq;
            bf16x8 af[4], bfv[4];
#pragma unroll
            for (int i = 0; i < 4; i++) {
                int row = wm + i * 16 + lm;
                af[i] = Av[row * 8 + (kc ^ (row & 7))];
            }
#pragma unroll
            for (int i = 0; i < 4; i++) {
                int row = wn + i * 16 + lm;
                bfv[i] = Bv[row * 8 + (kc ^ (row & 7))];
            }
#pragma unroll
            for (int mi = 0; mi < 4; mi++)
#pragma unroll
                for (int ni = 0; ni < 4; ni++)
                    acc[mi][ni] = __builtin_amdgcn_mfma_f32_16x16x32_bf16(af[mi], bfv[ni], acc[mi][ni], 0, 0, 0);
        }
        __syncthreads();
    }
#pragma unroll
    for (int mi = 0; mi < 4; mi++) {
#pragma unroll
        for (int ni = 0; ni < 4; ni++) {
            int colg = nbase + wn + ni * 16 + lm;
            float bias = b2[e * OUT_ + colg];
#pragma unroll
            for (int r = 0; r < 4; r++) {
                int rowl = wm + mi * 16 + lq * 4 + r;
                eout[(size_t)(slot_base + rowl) * OUT_ + colg] = acc[mi][ni][r] + bias;
            }
        }
    }
}

// ---------------- combine + loss: y[b] = sum_k gate_k * eout[slot_k]; block 2048 does loss ----------------
__global__ __launch_bounds__(256) void k_combine(
    const float* __restrict__ eout, const int* __restrict__ rowslot,
    const float* __restrict__ top_gate, float* __restrict__ y,
    const float* __restrict__ partial_imp, const int* __restrict__ counts,
    float* __restrict__ loss_out) {
    int t = threadIdx.x;
    if (blockIdx.x == B_ / 4) {  // loss block
        __shared__ float imp[16];
        if (t < 16) {
            float s = 0.f;
#pragma unroll
            for (int b = 0; b < HBLK; b++) s += partial_imp[b * 16 + t];
            imp[t] = s;
        }
        __syncthreads();
        if (t == 0) {
            float si = 0.f, sl = 0.f;
            for (int e = 0; e < E_; e++) { si += imp[e]; sl += (float)counts[e]; }
            float mi_ = si / (float)E_, ml_ = sl / (float)E_;
            float vi = 0.f, vl = 0.f;
            for (int e = 0; e < E_; e++) {
                float d = imp[e] - mi_; vi += d * d;
                float d2 = (float)counts[e] - ml_; vl += d2 * d2;
            }
            vi /= (float)(E_ - 1); vl /= (float)(E_ - 1);
            *loss_out = vi / (mi_ * mi_ + 1e-10f) + vl / (ml_ * ml_ + 1e-10f);
        }
        return;
    }
    int b = blockIdx.x * 4 + (t >> 6);
    int lane = t & 63;
    int s0 = rowslot[b * 3], s1 = rowslot[b * 3 + 1], s2 = rowslot[b * 3 + 2];
    float g0 = top_gate[b * 3], g1 = top_gate[b * 3 + 1], g2 = top_gate[b * 3 + 2];
    const float4* e4 = (const float4*)eout;
    float4 v0 = e4[(size_t)s0 * 64 + lane];
    float4 v1 = e4[(size_t)s1 * 64 + lane];
    float4 v2 = e4[(size_t)s2 * 64 + lane];
    float4 r;
    r.x = g0 * v0.x + g1 * v1.x + g2 * v2.x;
    r.y = g0 * v0.y + g1 * v1.y + g2 * v2.y;
    r.z = g0 * v0.z + g1 * v1.z + g2 * v2.z;
    r.w = g0 * v0.w + g1 * v1.w + g2 * v2.w;
    ((float4*)y)[(size_t)b * 64 + lane] = r;
}

extern "C" void kernel_launch(void* const* d_in, const int* in_sizes, int n_in,
                              void* d_out, int out_size, void* d_ws, size_t ws_size,
                              hipStream_t stream) {
    (void)in_sizes; (void)n_in; (void)out_size; (void)ws_size;
    const float* x = (const float*)d_in[0];
    const float* wgate = (const float*)d_in[1];
    const float* W1 = (const float*)d_in[2];
    const float* b1 = (const float*)d_in[3];
    const float* W2 = (const float*)d_in[4];
    const float* b2 = (const float*)d_in[5];
    float* y = (float*)d_out;  // [B*OUT] floats, then loss scalar at [B*OUT]

    char* p = (char*)d_ws;
    auto alloc = [&](size_t bytes) {
        char* q = p;
        p += (bytes + 255) & ~(size_t)255;
        return q;
    };
    bf16* xbf = (bf16*)alloc((size_t)B_ * IN_ * 2);          // 16 MB (dead after gemm1)
    bf16* w1t = (bf16*)alloc((size_t)E_ * H_ * IN_ * 2);     // 16 MB (dead after gemm1)
    bf16* w2t = (bf16*)alloc((size_t)E_ * OUT_ * H_ * 2);    // 4 MB
    bf16* h = (bf16*)alloc((size_t)MAXSLOTS * H_ * 2);       // 27 MB
    int* row_ids = (int*)alloc((size_t)MAXSLOTS * 4);
    int* rowslot = (int*)alloc((size_t)B_ * KTOP * 4);
    int* top_idx = (int*)alloc((size_t)B_ * KTOP * 4);
    float* top_gate = (float*)alloc((size_t)B_ * KTOP * 4);
    int* counts = (int*)alloc(E_ * 4);
    float* partial_imp = (float*)alloc(HBLK * E_ * 4);
    int* tile_expert = (int*)alloc(NTILES * 4);
    bf16* zero_row = (bf16*)alloc(IN_ * 2);
    float* wgT = (float*)alloc((size_t)E_ * IN_ * 4);        // 64 KB
    // eout (27 MB f32) aliases xbf+w1t (32 MB): both dead after gemm1.
    float* eout = (float*)xbf;

    k_setup<<<dim3(2729), dim3(256), 0, stream>>>(
        W1, w1t, W2, w2t, row_ids, wgate, wgT, zero_row, tile_expert);
    k_gating<<<dim3(B_ / 4), dim3(256), 0, stream>>>(x, wgT, xbf, top_idx, top_gate);
    k_dispatch<<<dim3(HBLK), dim3(256), 0, stream>>>(
        top_idx, top_gate, counts, tile_expert, row_ids, rowslot, partial_imp);
    k_gemm1<<<dim3(NTILES, H_ / 128), dim3(256), 0, stream>>>(
        xbf, w1t, b1, row_ids, tile_expert, zero_row, h);
    k_gemm2<<<dim3(NTILES, OUT_ / 128), dim3(256), 0, stream>>>(
        h, w2t, b2, tile_expert, eout);
    k_combine<<<dim3(B_ / 4 + 1), dim3(256), 0, stream>>>(
        eout, rowslot, top_gate, y, partial_imp, counts, y + (size_t)B_ * OUT_);
}